// Round 10
// baseline (239.904 us; speedup 1.0000x reference)
//
#include <hip/hip_runtime.h>

#define BATCHES 8
#define NPTS    100000
#define NPOINT  64
#define BPB     16                    // blocks per batch
#define NTHREADS 512                  // 8 waves/block (2 per SIMD)
#define WPB     (NTHREADS / 64)
#define TPB     (BPB * NTHREADS)      // threads per batch = 8192
#define KMAX    13                    // ceil(NPTS / TPB)
#define TAILN   (NPTS - (KMAX - 1) * TPB)

// workspace layout
#define WS_BARY_OFF 0                                    // [B][BPB][3] double = 3072 B
#define WS_CNT_OFF  3072                                 // [B] u32
#define WS_SLOT_OFF 4096                                 // [B][NPOINT][BPB] slots, stride SU u64
#define WS_ZERO_BYTES 4096                               // only cnt+bary need zeroing

// contraction-free f32 squared distance, numpy sum order (dx*dx + dy*dy) + dz*dz
__device__ __forceinline__ float sq3(float dx, float dy, float dz) {
    return __fadd_rn(__fadd_rn(__fmul_rn(dx, dx), __fmul_rn(dy, dy)), __fmul_rn(dz, dz));
}

__global__ __launch_bounds__(NTHREADS, 4)
void fps_kernel(const float* __restrict__ xyz, float* __restrict__ out,
                unsigned char* __restrict__ ws, int SU /* slot stride in u64 */)
{
    double* baryPart = (double*)(ws + WS_BARY_OFF);
    unsigned int* cnt = (unsigned int*)(ws + WS_CNT_OFF);
    unsigned long long* slots = (unsigned long long*)(ws + WS_SLOT_OFF);

    const int b    = blockIdx.x & 7;          // XCD-pin heuristic (perf only)
    const int blk  = blockIdx.x >> 3;         // 0..15 within batch
    const int tid  = threadIdx.x;
    const int wid  = tid >> 6;
    const int lane = tid & 63;
    const int t    = blk * NTHREADS + tid;    // 0..TPB-1 within batch

    const float* xb = xyz + (size_t)b * NPTS * 3;

    __shared__ double bred[WPB][3];
    __shared__ unsigned long long kcomb[WPB][5];   // {key, xw, yw, zw}, stride 5 (no bank conflict)
    __shared__ float s_c[3];

    float px[KMAX], py[KMAX], pz[KMAX], dist[KMAX];
    float bestd[KMAX]; int besti[KMAX];
    const int nk = (t < TAILN) ? KMAX : (KMAX - 1);

    // ---- load points into registers; double partial sums for the mean ----
    double sx = 0.0, sy = 0.0, sz = 0.0;
    #pragma unroll
    for (int k = 0; k < KMAX; k++) {
        if (k < nk) {
            int p = t + k * TPB;
            float x = xb[p * 3 + 0], y = xb[p * 3 + 1], z = xb[p * 3 + 2];
            px[k] = x; py[k] = y; pz[k] = z; dist[k] = 1e10f;
            bestd[k] = 3.4e38f; besti[k] = 0;
            sx += (double)x; sy += (double)y; sz += (double)z;
        }
    }
    for (int off = 32; off > 0; off >>= 1) {
        sx += __shfl_down(sx, off); sy += __shfl_down(sy, off); sz += __shfl_down(sz, off);
    }
    if (lane == 0) { bred[wid][0] = sx; bred[wid][1] = sy; bred[wid][2] = sz; }
    __syncthreads();
    if (tid == 0) {
        double ax = 0, ay = 0, az = 0;
        for (int w = 0; w < WPB; w++) { ax += bred[w][0]; ay += bred[w][1]; az += bred[w][2]; }
        double* dst = baryPart + ((size_t)b * BPB + blk) * 3;
        dst[0] = ax; dst[1] = ay; dst[2] = az;
        __hip_atomic_fetch_add(&cnt[b], 1u, __ATOMIC_ACQ_REL, __HIP_MEMORY_SCOPE_AGENT);
        while (__hip_atomic_load(&cnt[b], __ATOMIC_ACQUIRE, __HIP_MEMORY_SCOPE_AGENT) < BPB)
            __builtin_amdgcn_s_sleep(2);
        double mx = 0, my = 0, mz = 0;
        for (int q = 0; q < BPB; q++) {       // deterministic fixed order
            const double* s2 = baryPart + ((size_t)b * BPB + q) * 3;
            mx += s2[0]; my += s2[1]; mz += s2[2];
        }
        s_c[0] = (float)(mx / (double)NPTS);
        s_c[1] = (float)(my / (double)NPTS);
        s_c[2] = (float)(mz / (double)NPTS);
    }
    __syncthreads();
    const float bx = s_c[0], by = s_c[1], bz = s_c[2];

    // ---- per-thread candidate 0: farthest from barycenter (value-tracked coords) ----
    float bd = -1.0f, bpx = 0.f, bpy = 0.f, bpz = 0.f; int bp = 0;
    #pragma unroll
    for (int k = 0; k < KMAX; k++) {
        if (k < nk) {
            int p = t + k * TPB;
            float d = sq3(__fsub_rn(px[k], bx), __fsub_rn(py[k], by), __fsub_rn(pz[k], bz));
            if (d > bd) { bd = d; bp = p; bpx = px[k]; bpy = py[k]; bpz = pz[k]; }
        }
    }
    unsigned long long key = (((unsigned long long)__float_as_uint(bd)) << 32)
                             | (unsigned)(0xFFFFFFFFu - (unsigned)bp);   // low32 >= 0xFFFE7960

    // ================= 64 rounds: padded-slot exchange, coords in slot =================
    for (int e = 0; e < NPOINT; e++) {
        // A: wave xor-broadcast max; winning lane posts {key,coords} to LDS
        unsigned long long wmax = key;
        for (int m = 32; m > 0; m >>= 1) {
            unsigned long long o = __shfl_xor(wmax, m); if (o > wmax) wmax = o;
        }
        if (key == wmax) {                    // exactly one lane (keys unique)
            kcomb[wid][0] = wmax;
            kcomb[wid][1] = (((unsigned long long)__float_as_uint(bpx)) << 32)
                            | (0x5A5A0000u | ((unsigned)e << 8) | 1u);
            kcomb[wid][2] = (((unsigned long long)__float_as_uint(bpy)) << 32)
                            | (0x5A5A0000u | ((unsigned)e << 8) | 2u);
            kcomb[wid][3] = (((unsigned long long)__float_as_uint(bpz)) << 32)
                            | (0x5A5A0000u | ((unsigned)e << 8) | 3u);
        }
        __syncthreads();                      // B: candidates visible to wave0

        if (wid == 0) {
            unsigned long long* srow = slots + ((size_t)b * NPOINT + e) * BPB * SU;
            // C: block combine (keys) + ballot winner wave; 4 lanes post the package
            unsigned long long v = (lane < WPB) ? kcomb[lane][0] : 0ull;
            unsigned long long bb = v;
            for (int m = 4; m > 0; m >>= 1) {
                unsigned long long o = __shfl_xor(bb, m, 8); if (o > bb) bb = o;
            }
            unsigned long long bmask = __ballot(v == bb && lane < WPB);
            int winwid = __ffsll(bmask) - 1;
            if (lane < 4) {
                unsigned long long wv = kcomb[winwid][lane];
                __hip_atomic_store(&srow[(size_t)blk * SU + lane], wv,
                                   __ATOMIC_RELAXED, __HIP_MEMORY_SCOPE_AGENT);
            }
            // D: 64 lanes poll one word each (16 slots x 4 words), tag-validated
            const int sl = lane >> 2, j = lane & 3;
            unsigned long long* myp = &srow[(size_t)sl * SU + j];
            const unsigned ctag = 0x5A5A0000u | ((unsigned)e << 8) | (unsigned)j;
            unsigned long long val;
            for (;;) {
                val = __hip_atomic_load(myp, __ATOMIC_RELAXED, __HIP_MEMORY_SCOPE_AGENT);
                unsigned lo = (unsigned)val;
                bool ok = (j == 0) ? (lo >= 0xFFFE0000u) : (lo == ctag);
                if (ok) break;
            }
            // E: winner extraction fully in-register
            unsigned long long kv = (j == 0) ? val : 0ull;
            for (int m = 32; m > 0; m >>= 1) {
                unsigned long long o = __shfl_xor(kv, m); if (o > kv) kv = o;
            }
            unsigned long long mask = __ballot(val == kv);   // key lane of winning slot
            int src = __ffsll(mask) - 1;
            unsigned long long xw = __shfl(val, src + 1);
            unsigned long long yw = __shfl(val, src + 2);
            unsigned long long zw = __shfl(val, src + 3);
            if (lane == 0) {
                int f = (int)(0xFFFFFFFFu - (unsigned)(kv & 0xFFFFFFFFull));
                float cx = __uint_as_float((unsigned)(xw >> 32));
                float cy = __uint_as_float((unsigned)(yw >> 32));
                float cz = __uint_as_float((unsigned)(zw >> 32));
                s_c[0] = cx; s_c[1] = cy; s_c[2] = cz;
                if (blk == 0) {
                    out[((size_t)b * NPOINT + e) * 3 + 0] = cx;
                    out[((size_t)b * NPOINT + e) * 3 + 1] = cy;
                    out[((size_t)b * NPOINT + e) * 3 + 2] = cz;
                    out[(size_t)BATCHES * NPOINT * 3 + b * NPOINT + e] = (float)f;
                }
            }
        }
        __syncthreads();                      // winner coords published
        if (e == NPOINT - 1) break;

        // distance update + assignment fold + next candidate
        const float cx = s_c[0], cy = s_c[1], cz = s_c[2];
        bd = -1.0f; bp = 0; bpx = 0.f; bpy = 0.f; bpz = 0.f;
        #pragma unroll
        for (int k = 0; k < KMAX; k++) {
            if (k < nk) {
                float d = sq3(__fsub_rn(px[k], cx), __fsub_rn(py[k], cy), __fsub_rn(pz[k], cz));
                if (d < bestd[k]) { bestd[k] = d; besti[k] = e; }   // argmin fold (first-index)
                float nd = fminf(dist[k], d);                       // winner's d==0 exactly
                dist[k] = nd;
                int p = t + k * TPB;
                if (nd > bd) { bd = nd; bp = p; bpx = px[k]; bpy = py[k]; bpz = pz[k]; }
            }
        }
        key = (((unsigned long long)__float_as_uint(bd)) << 32)
              | (unsigned)(0xFFFFFFFFu - (unsigned)bp);
    }

    // ---- final assignment pass vs centroid 63 ----
    {
        const float cx = s_c[0], cy = s_c[1], cz = s_c[2];
        #pragma unroll
        for (int k = 0; k < KMAX; k++) {
            if (k < nk) {
                float d = sq3(__fsub_rn(px[k], cx), __fsub_rn(py[k], cy), __fsub_rn(pz[k], cz));
                if (d < bestd[k]) { bestd[k] = d; besti[k] = NPOINT - 1; }
            }
        }
    }

    float* outClust = out + (size_t)BATCHES * NPOINT * 3 + (size_t)BATCHES * NPOINT;
    #pragma unroll
    for (int k = 0; k < KMAX; k++)
        if (k < nk) outClust[(size_t)b * NPTS + t + k * TPB] = (float)besti[k];
}

extern "C" void kernel_launch(void* const* d_in, const int* in_sizes, int n_in,
                              void* d_out, int out_size, void* d_ws, size_t ws_size,
                              hipStream_t stream) {
    const float* xyz = (const float*)d_in[0];
    float* out = (float*)d_out;
    // pick slot stride by available workspace (deterministic: depends only on ws_size)
    int SU = 16;                                          // 128 B per slot (own cache line)
    if (ws_size < WS_SLOT_OFF + (size_t)BATCHES * NPOINT * BPB * 16 * 8) SU = 4;   // 32 B
    if (ws_size < WS_SLOT_OFF + (size_t)BATCHES * NPOINT * BPB * 4 * 8)  SU = 1;   // 8 B (key..)
    // SU==1 can't hold coords; guard: SU>=4 required, ws_size is known ample in this harness.
    if (SU < 4) SU = 4;
    hipMemsetAsync(d_ws, 0, WS_ZERO_BYTES, stream);       // cnt + barycenter partials only
    fps_kernel<<<dim3(BATCHES * BPB), dim3(NTHREADS), 0, stream>>>(
        xyz, out, (unsigned char*)d_ws, SU);
}